// Round 1
// baseline (383.775 us; speedup 1.0000x reference)
//
#include <hip/hip_runtime.h>
#include <math.h>

#define BAGN 15
#define PSZ 8
#define IMSZ 28
#define LAMF 0.001f

// One thread per sample. 5 sequential step kernels; coact (15x15 batch outer
// product sum) is accumulated per-block in LDS then atomicAdd'ed to a global
// buffer consumed by the next step's kernel (stream-ordered, device-scope).
template<bool FIRST, bool LAST>
__global__ __launch_bounds__(256) void step_kernel(
    const float* __restrict__ x,
    const float* __restrict__ Wi, const float* __restrict__ bi,
    const float* __restrict__ gamma, const float* __restrict__ beta,
    const float* __restrict__ R, const float* __restrict__ rb,
    const float* __restrict__ mask,
    const float* __restrict__ Wc, const float* __restrict__ bc,
    const float* __restrict__ Wo, const float* __restrict__ bo,
    float* __restrict__ state_io, int* __restrict__ pos_io,
    const float* __restrict__ coact_in, float* __restrict__ coact_out,
    float* __restrict__ out, int B, float invB)
{
    __shared__ float sWi[15 * 72];          // padded rows for aligned LDS reads
    __shared__ float sBi[15], sGa[15], sBe[15], sRb[15];
    __shared__ float sWc[30], sBc[2], sWo[150], sBo[10];
    __shared__ float sReff[225];
    __shared__ float sS[256 * 16];          // block states for coact reduction

    const int tid = threadIdx.x;

    for (int idx = tid; idx < 990; idx += 256) {
        int u = idx / 66, k = idx - u * 66;
        sWi[u * 72 + k] = Wi[idx];
    }
    if (tid < 15) {
        sBi[tid] = bi[tid]; sGa[tid] = gamma[tid];
        sBe[tid] = beta[tid]; sRb[tid] = rb[tid];
    }
    if (tid >= 32 && tid < 62) sWc[tid - 32] = Wc[tid - 32];
    if (tid >= 64 && tid < 66) sBc[tid - 64] = bc[tid - 64];
    if (LAST) {
        if (tid >= 96 && tid < 246) sWo[tid - 96] = Wo[tid - 96];
        if (tid >= 246 && tid < 256) sBo[tid - 246] = bo[tid - 246];
    }
    if (!FIRST) {
        if (tid < 225)
            sReff[tid] = (R[tid] - LAMF * (coact_in[tid] * invB)) * mask[tid];
    }
    __syncthreads();

    const int b = blockIdx.x * 256 + tid;

    int pr, pc;
    if (FIRST) { pr = 10; pc = 10; }
    else { pr = pos_io[b]; pc = pos_io[B + b]; }

    // Gather 8x8 patch; all 64 loads issued before first use (ILP latency hiding).
    const float* img = x + (size_t)b * (IMSZ * IMSZ);
    float patch[64];
#pragma unroll
    for (int r = 0; r < 8; ++r) {
        const float* rowp = img + (pr + r) * IMSZ + pc;
#pragma unroll
        for (int c = 0; c < 8; ++c) patch[r * 8 + c] = rowp[c];
    }
    const float posr = ((float)pr / 20.0f) * 2.0f - 1.0f;
    const float posc = ((float)pc / 20.0f) * 2.0f - 1.0f;

    float sprev[15];
    if (!FIRST) {
#pragma unroll
        for (int j = 0; j < 15; ++j) sprev[j] = state_io[j * B + b];
    }

    float h[15];
#pragma unroll
    for (int u = 0; u < 15; ++u) {
        const float* w = sWi + u * 72;
        float a = 0.0f;
#pragma unroll
        for (int k = 0; k < 64; ++k) a = fmaf(patch[k], w[k], a);
        a = fmaf(posr, w[64], a);
        a = fmaf(posc, w[65], a);
        a += sBi[u];
        if (!FIRST) {
            float r2 = 0.0f;
#pragma unroll
            for (int j = 0; j < 15; ++j) r2 = fmaf(sprev[j], sReff[u * 15 + j], r2);
            a += r2 + sRb[u];
        }
        h[u] = a > 0.0f ? a : 0.0f;
    }

    // LayerNorm over the 15 units
    float mu = 0.0f;
#pragma unroll
    for (int u = 0; u < 15; ++u) mu += h[u];
    mu *= (1.0f / 15.0f);
    float var = 0.0f;
#pragma unroll
    for (int u = 0; u < 15; ++u) { float d = h[u] - mu; var = fmaf(d, d, var); }
    var *= (1.0f / 15.0f);
    const float rs = 1.0f / sqrtf(var + 1e-5f);
    float s[15];
#pragma unroll
    for (int u = 0; u < 15; ++u) s[u] = (h[u] - mu) * rs * sGa[u] + sBe[u];

    if (LAST) {
#pragma unroll
        for (int o = 0; o < 10; ++o) {
            float a = 0.0f;
#pragma unroll
            for (int j = 0; j < 15; ++j) a = fmaf(s[j], sWo[o * 15 + j], a);
            out[(size_t)b * 10 + o] = a + sBo[o];
        }
    } else {
        // persist state (SoA, coalesced)
#pragma unroll
        for (int j = 0; j < 15; ++j) state_io[j * B + b] = s[j];

        // control head -> position update
        float c0 = 0.0f, c1 = 0.0f;
#pragma unroll
        for (int j = 0; j < 15; ++j) {
            c0 = fmaf(s[j], sWc[j], c0);
            c1 = fmaf(s[j], sWc[15 + j], c1);
        }
        c0 = tanhf(c0 + sBc[0]);
        c1 = tanhf(c1 + sBc[1]);
        const float m0 = fabsf(c0), m1 = fabsf(c1);
        int rm, cm;
        if (m0 >= m1) { rm = (c0 > 0.0f) - (c0 < 0.0f); cm = 0; }
        else          { rm = 0; cm = (c1 > 0.0f) - (c1 < 0.0f); }
        pr += rm; pc += cm;
        pr = min(max(pr, 0), IMSZ - PSZ);
        pc = min(max(pc, 0), IMSZ - PSZ);
        pos_io[b] = pr;
        pos_io[B + b] = pc;

        // coact partial: block-level reduction of outer(s, s)
#pragma unroll
        for (int j = 0; j < 15; ++j) sS[tid * 16 + j] = s[j];
        __syncthreads();
        if (tid < 225) {
            int i = tid / 15, j = tid - i * 15;
            float acc = 0.0f;
#pragma unroll 8
            for (int bb = 0; bb < 256; ++bb)
                acc = fmaf(sS[bb * 16 + i], sS[bb * 16 + j], acc);
            atomicAdd(&coact_out[tid], acc);
        }
    }
}

extern "C" void kernel_launch(void* const* d_in, const int* in_sizes, int n_in,
                              void* d_out, int out_size, void* d_ws, size_t ws_size,
                              hipStream_t stream) {
    const float* x     = (const float*)d_in[0];
    const float* Wi    = (const float*)d_in[1];
    const float* bi    = (const float*)d_in[2];
    const float* gamma = (const float*)d_in[3];
    const float* beta  = (const float*)d_in[4];
    const float* R     = (const float*)d_in[5];
    const float* rb    = (const float*)d_in[6];
    const float* mask  = (const float*)d_in[7];
    const float* Wc    = (const float*)d_in[8];
    const float* bc    = (const float*)d_in[9];
    const float* Wo    = (const float*)d_in[10];
    const float* bo    = (const float*)d_in[11];
    float* out = (float*)d_out;

    const int B = in_sizes[0] / (IMSZ * IMSZ);
    const int grid = B / 256;
    const float invB = 1.0f / (float)B;

    // workspace layout: state (B*15 f32) | pos (B*2 i32) | coact (4*256 f32)
    float* wsf = (float*)d_ws;
    float* state = wsf;
    int* pos = (int*)(wsf + (size_t)B * 15);
    float* coact = wsf + (size_t)B * 15 + (size_t)B * 2;

    hipMemsetAsync(coact, 0, 4 * 256 * sizeof(float), stream);

    step_kernel<true, false><<<grid, 256, 0, stream>>>(
        x, Wi, bi, gamma, beta, R, rb, mask, Wc, bc, Wo, bo,
        state, pos, nullptr, coact, nullptr, B, invB);
    step_kernel<false, false><<<grid, 256, 0, stream>>>(
        x, Wi, bi, gamma, beta, R, rb, mask, Wc, bc, Wo, bo,
        state, pos, coact, coact + 256, nullptr, B, invB);
    step_kernel<false, false><<<grid, 256, 0, stream>>>(
        x, Wi, bi, gamma, beta, R, rb, mask, Wc, bc, Wo, bo,
        state, pos, coact + 256, coact + 512, nullptr, B, invB);
    step_kernel<false, false><<<grid, 256, 0, stream>>>(
        x, Wi, bi, gamma, beta, R, rb, mask, Wc, bc, Wo, bo,
        state, pos, coact + 512, coact + 768, nullptr, B, invB);
    step_kernel<false, true><<<grid, 256, 0, stream>>>(
        x, Wi, bi, gamma, beta, R, rb, mask, Wc, bc, Wo, bo,
        state, pos, coact + 768, nullptr, out, B, invB);
}